// Round 14
// baseline (342.727 us; speedup 1.0000x reference)
//
#include <hip/hip_runtime.h>
#include <math.h>

#define NC    30
#define D     300
#define WIN   100
#define TOPK  25
#define NEGV  -1e10f
#define NKS   19           // 19*16 = 304 >= 300
#define AST   312          // A-plane LDS row stride in shorts (624 B)

typedef __attribute__((ext_vector_type(8)))  short short8;
typedef __attribute__((ext_vector_type(16))) float f32x16;
typedef __attribute__((ext_vector_type(4)))  unsigned int uint4v;

__device__ inline unsigned short bftrunc(float f) {
    return (unsigned short)(__builtin_bit_cast(unsigned int, f) >> 16);
}
__device__ inline float bfval(unsigned short b) {
    return __builtin_bit_cast(float, (unsigned int)b << 16);
}
__device__ inline void split8(const float* v, short8& hi, short8& lo) {
    #pragma unroll
    for (int j = 0; j < 8; ++j) {
        unsigned short hb = bftrunc(v[j]);
        float lf = v[j] - bfval(hb);
        hi[j] = (short)hb;
        lo[j] = (short)bftrunc(lf);
    }
}

__global__ __launch_bounds__(256, 4)
void fused_mention_kernel(const float* __restrict__ E,
                          const float* __restrict__ T,
                          const void*  __restrict__ maskp,
                          const float* __restrict__ B1,
                          const float* __restrict__ B2,
                          float* __restrict__ out)
{
    const int n     = blockIdx.x;
    const int tid   = threadIdx.x;
    const int wv    = tid >> 6;
    const int lane  = tid & 63;
    const int arow  = lane & 31;          // candidate row (A) / token col (B)
    const int khalf = (lane >> 5) * 8;

    __shared__ __align__(16) short Ah[NC * AST];   // 18.7 KB bf16-hi of E*B2
    __shared__ __align__(16) short Al[NC * AST];   // 18.7 KB bf16-lo
    __shared__ float ts[WIN];

    // ---- mask dtype detect, per-wave: int32 has zero bytes at %4!=0 ----
    int found;
    {
        const uint4v* m4 = (const uint4v*)maskp;
        uint4v w = m4[wv * 64 + lane];
        found = (((w.x | w.y | w.z | w.w) & 0xFFFFFF00u) != 0u) ? 1 : 0;
    }
    const bool bytemask = (__ballot(found) != 0ULL);

    // ---- valid-prefix length L, per-wave ----
    int v0m = 0, v1m = 0;
    if (bytemask) {
        const unsigned char* mb = (const unsigned char*)maskp + (size_t)n * WIN;
        v0m = mb[lane] != 0;
        if (lane + 64 < WIN) v1m = mb[lane + 64] != 0;
    } else {
        const int* mi = (const int*)maskp + (size_t)n * WIN;
        v0m = mi[lane] != 0;
        if (lane + 64 < WIN) v1m = mi[lane + 64] != 0;
    }
    const int L  = __popcll(__ballot(v0m)) + __popcll(__ballot(v1m));
    const int Lc = (L > 0) ? L : 1;

    // ---- B1 == B2 check (enables vals-from-scores identity) ----
    int neq = 0;
    #pragma unroll
    for (int k = 0; k < 5; ++k) {
        const int d = lane + 64 * k;
        if (d < D) neq |= (B1[d] != B2[d]) ? 1 : 0;
    }
    const bool beq = (__ballot(neq) == 0ULL);   // block-uniform

    // ---- stage A = E * B_diag2 into LDS as bf16 hi/lo ----
    {
        const int srow = tid & 31;        // rows 30,31 idle
        const int scol = tid >> 5;        // 0..7
        if (srow < NC) {
            #pragma unroll
            for (int k = 0; k < 5; ++k) {
                const int c8 = scol + 8 * k;          // 0..39
                if (c8 < 38) {
                    const int col = c8 * 8;
                    const float* src = E + ((size_t)n * NC + srow) * D + col;
                    float v[8];
                    float4 q0 = *reinterpret_cast<const float4*>(src);
                    float4 b0 = *reinterpret_cast<const float4*>(B2 + col);
                    v[0] = q0.x * b0.x; v[1] = q0.y * b0.y;
                    v[2] = q0.z * b0.z; v[3] = q0.w * b0.w;
                    if (c8 < 37) {
                        float4 q1 = *reinterpret_cast<const float4*>(src + 4);
                        float4 b1 = *reinterpret_cast<const float4*>(B2 + col + 4);
                        v[4] = q1.x * b1.x; v[5] = q1.y * b1.y;
                        v[6] = q1.z * b1.z; v[7] = q1.w * b1.w;
                    } else {
                        v[4] = v[5] = v[6] = v[7] = 0.f;
                    }
                    short8 hi, lo;
                    split8(v, hi, lo);
                    *reinterpret_cast<short8*>(Ah + srow * AST + col) = hi;
                    *reinterpret_cast<short8*>(Al + srow * AST + col) = lo;
                }
            }
        }
    }

    const int ntiles = (L + 31) >> 5;
    const int t0 = wv * 32;
    const float* Tn = T + (size_t)n * WIN * D;
    const float* bp = Tn + (size_t)min(t0 + arow, Lc - 1) * D;
    const int aoff = min(arow, NC - 1) * AST + khalf;

    // ---- preload approx ring steps 0..3 BEFORE the barrier ----
    float4 q0r[4], q1r[4];
    if (wv < ntiles) {
        #pragma unroll
        for (int s = 0; s < 4; ++s) {
            const int kb = 16 * s + khalf;
            q0r[s] = *reinterpret_cast<const float4*>(bp + kb);
            q1r[s] = *reinterpret_cast<const float4*>(bp + kb + 4);
        }
    }
    __syncthreads();                              // A staged

    // ---- APPROX score GEMM (hi*hi only): selection-grade precision ----
    float m = NEGV;
    if (wv < ntiles) {
        f32x16 c;
        #pragma unroll
        for (int r = 0; r < 16; ++r) c[r] = 0.f;
        #pragma unroll
        for (int s = 0; s < NKS; ++s) {
            const int slot = s & 3;
            float4 q0 = q0r[slot], q1 = q1r[slot];
            if (s + 4 < NKS) {
                const int kb2 = 16 * (s + 4) + khalf;
                q0r[slot] = *reinterpret_cast<const float4*>(bp + kb2);
                q1r[slot] = (kb2 + 8 <= D)
                          ? *reinterpret_cast<const float4*>(bp + kb2 + 4)
                          : make_float4(0.f, 0.f, 0.f, 0.f);
            }
            short8 ah = *reinterpret_cast<const short8*>(Ah + aoff + 16 * s);
            short8 bh;
            bh[0] = (short)bftrunc(q0.x); bh[1] = (short)bftrunc(q0.y);
            bh[2] = (short)bftrunc(q0.z); bh[3] = (short)bftrunc(q0.w);
            bh[4] = (short)bftrunc(q1.x); bh[5] = (short)bftrunc(q1.y);
            bh[6] = (short)bftrunc(q1.z); bh[7] = (short)bftrunc(q1.w);
            c = __builtin_amdgcn_mfma_f32_32x32x16_bf16(ah, bh, c, 0, 0, 0);
        }
        if (lane >= 32) { c[14] = -__builtin_inff(); c[15] = -__builtin_inff(); }
        m = c[0];
        #pragma unroll
        for (int r = 1; r < 16; ++r) m = fmaxf(m, c[r]);
        m = fmaxf(m, __shfl_xor(m, 32));
    }
    if (lane < 32 && t0 + arow < WIN)
        ts[t0 + arow] = (wv < ntiles && t0 + arow < L) ? m : NEGV;
    __syncthreads();                              // ts complete

    if (wv != 0) return;                          // waves 1-3 retire (no more barriers)

    // ---- wave 0: top-25 on approx scores (lower-index tie-break) ----
    const float NINF = -__builtin_inff();
    float va = ts[lane];
    float vb = (lane + 64 < WIN) ? ts[lane + 64] : NINF;
    int ixr = 0;
    for (int t = 0; t < TOPK; ++t) {
        float v0; int i0;
        if (vb > va) { v0 = vb; i0 = lane + 64; } else { v0 = va; i0 = lane; }
        #pragma unroll
        for (int s = 32; s >= 1; s >>= 1) {
            float ov = __shfl_xor(v0, s);
            int   oi = __shfl_xor(i0, s);
            if (ov > v0 || (ov == v0 && oi < i0)) { v0 = ov; i0 = oi; }
        }
        if (lane == t) ixr = i0;
        if (i0 == lane) va = NINF;
        else if (i0 == lane + 64) vb = NINF;
    }
    // column view: col = arow; winner index per column (cols 25-31 dup of 24)
    const int bidx_col = __shfl(ixr, min(arow, TOPK - 1));
    const bool colok = (arow < TOPK) && (bidx_col < L);

    // ---- EXACT 3-term GEMM on the winner tile ----
    const float* wp = Tn + (size_t)bidx_col * D;
    f32x16 c;  f32x16 cB;
    #pragma unroll
    for (int r = 0; r < 16; ++r) { c[r] = 0.f; cB[r] = 0.f; }
    {
        float4 e0r[4], e1r[4];
        #pragma unroll
        for (int s = 0; s < 4; ++s) {
            const int kb = 16 * s + khalf;
            e0r[s] = *reinterpret_cast<const float4*>(wp + kb);
            e1r[s] = *reinterpret_cast<const float4*>(wp + kb + 4);
        }
        #pragma unroll
        for (int s = 0; s < NKS; ++s) {
            const int slot = s & 3;
            float4 q0 = e0r[slot], q1 = e1r[slot];
            if (s + 4 < NKS) {
                const int kb2 = 16 * (s + 4) + khalf;
                e0r[slot] = *reinterpret_cast<const float4*>(wp + kb2);
                e1r[slot] = (kb2 + 8 <= D)
                          ? *reinterpret_cast<const float4*>(wp + kb2 + 4)
                          : make_float4(0.f, 0.f, 0.f, 0.f);
            }
            short8 ah = *reinterpret_cast<const short8*>(Ah + aoff + 16 * s);
            short8 al = *reinterpret_cast<const short8*>(Al + aoff + 16 * s);
            float v[8] = {q0.x, q0.y, q0.z, q0.w, q1.x, q1.y, q1.z, q1.w};
            short8 bh, bl;
            split8(v, bh, bl);
            if (s & 1) {
                cB = __builtin_amdgcn_mfma_f32_32x32x16_bf16(ah, bh, cB, 0, 0, 0);
                cB = __builtin_amdgcn_mfma_f32_32x32x16_bf16(al, bh, cB, 0, 0, 0);
                cB = __builtin_amdgcn_mfma_f32_32x32x16_bf16(ah, bl, cB, 0, 0, 0);
            } else {
                c  = __builtin_amdgcn_mfma_f32_32x32x16_bf16(ah, bh, c, 0, 0, 0);
                c  = __builtin_amdgcn_mfma_f32_32x32x16_bf16(al, bh, c, 0, 0, 0);
                c  = __builtin_amdgcn_mfma_f32_32x32x16_bf16(ah, bl, c, 0, 0, 0);
            }
        }
        #pragma unroll
        for (int r = 0; r < 16; ++r) c[r] += cB[r];
    }
    // exact per-winner token score: max over candidate rows (pad rows -> -inf)
    if (lane >= 32) { c[14] = NINF; c[15] = NINF; }
    float mt = c[0];
    #pragma unroll
    for (int r = 1; r < 16; ++r) mt = fmaxf(mt, c[r]);
    mt = fmaxf(mt, __shfl_xor(mt, 32));
    mt = colok ? mt : NEGV;                      // masked/dup winners -> exact -1e10

    // ---- exact softmax over 25 winners (per-half butterflies; halves identical) ----
    float mx = mt;
    #pragma unroll
    for (int s = 16; s >= 1; s >>= 1) mx = fmaxf(mx, __shfl_xor(mx, s));
    float p = (arow < TOPK) ? expf(mt - mx) : 0.f;
    float s1 = p;
    #pragma unroll
    for (int s = 16; s >= 1; s >>= 1) s1 += __shfl_xor(s1, s);
    p = p / s1;
    float s2 = p;   // reference renormalizes a second time
    #pragma unroll
    for (int s = 16; s >= 1; s >>= 1) s2 += __shfl_xor(s2, s);
    p = p / s2;

    if (beq) {
        // ---- vals[row] = sum_t p_t * S[row, t]: butterfly of p*c over columns ----
        float vacc[16];
        #pragma unroll
        for (int r = 0; r < 16; ++r) {
            float s = p * c[r];
            s += __shfl_xor(s, 1);  s += __shfl_xor(s, 2);
            s += __shfl_xor(s, 4);  s += __shfl_xor(s, 8);
            s += __shfl_xor(s, 16);
            vacc[r] = s;
        }
        if ((lane & 31) == 0) {                  // lanes 0 and 32
            #pragma unroll
            for (int r = 0; r < 16; ++r) {
                const int row = (r & 3) + 8 * (r >> 2) + 4 * (lane >> 5);
                if (row < NC) out[(size_t)n * NC + row] = vacc[r];
            }
        }
    } else {
        // ---- fallback (B1 != B2): fcs + vals, single-wave, register-resident ----
        float fc[5] = {0.f, 0.f, 0.f, 0.f, 0.f};
        for (int t = 0; t < TOPK; ++t) {
            const float pb = __shfl(p, t);
            const int   ib = __shfl(bidx_col, t);
            const float* Trow = Tn + (size_t)ib * D;
            #pragma unroll
            for (int c5 = 0; c5 < 5; ++c5) {
                const int dim = c5 * 64 + lane;
                if (dim < D) fc[c5] += pb * Trow[dim];
            }
        }
        float acc2[NC];
        #pragma unroll
        for (int cc = 0; cc < NC; ++cc) acc2[cc] = 0.f;
        #pragma unroll
        for (int c5 = 0; c5 < 5; ++c5) {
            const int dim  = c5 * 64 + lane;
            const int dimc = min(dim, D - 1);
            const float g  = (dim < D) ? B1[dim] * fc[c5] : 0.f;
            const float* Eb = E + (size_t)n * NC * D + dimc;
            #pragma unroll
            for (int cc = 0; cc < NC; ++cc)
                acc2[cc] += Eb[(size_t)cc * D] * g;
        }
        #pragma unroll
        for (int cc = 0; cc < NC; ++cc) {
            float s = acc2[cc];
            #pragma unroll
            for (int sft = 32; sft >= 1; sft >>= 1) s += __shfl_xor(s, sft);
            if (lane == cc) out[(size_t)n * NC + cc] = s;
        }
    }
}

extern "C" void kernel_launch(void* const* d_in, const int* in_sizes, int n_in,
                              void* d_out, int out_size, void* d_ws, size_t ws_size,
                              hipStream_t stream)
{
    const float* E  = (const float*)d_in[0];
    const float* T  = (const float*)d_in[1];
    const void*  M  = d_in[2];
    const float* B1 = (const float*)d_in[3];
    const float* B2 = (const float*)d_in[4];
    float* out = (float*)d_out;
    const int n = in_sizes[0] / (NC * D);   // number of mentions
    fused_mention_kernel<<<n, 256, 0, stream>>>(E, T, M, B1, B2, out);
}

// Round 15
// 289.536 us; speedup vs baseline: 1.1837x; 1.1837x over previous
//
#include <hip/hip_runtime.h>
#include <math.h>

#define NC    30
#define D     300
#define WIN   100
#define TOPK  25
#define NEGV  -1e10f
#define NKS   19           // 19*16 = 304 >= 300
#define AST   312          // A-plane LDS row stride in shorts (624 B)

typedef __attribute__((ext_vector_type(8)))  short short8;
typedef __attribute__((ext_vector_type(16))) float f32x16;
typedef __attribute__((ext_vector_type(4)))  unsigned int uint4v;

__device__ inline unsigned short bftrunc(float f) {
    return (unsigned short)(__builtin_bit_cast(unsigned int, f) >> 16);
}
__device__ inline float bfval(unsigned short b) {
    return __builtin_bit_cast(float, (unsigned int)b << 16);
}
__device__ inline void split8(const float* v, short8& hi, short8& lo) {
    #pragma unroll
    for (int j = 0; j < 8; ++j) {
        unsigned short hb = bftrunc(v[j]);
        float lf = v[j] - bfval(hb);
        hi[j] = (short)hb;
        lo[j] = (short)bftrunc(lf);
    }
}

__global__ __launch_bounds__(256, 4)
void fused_mention_kernel(const float* __restrict__ E,
                          const float* __restrict__ T,
                          const void*  __restrict__ maskp,
                          const float* __restrict__ B1,
                          const float* __restrict__ B2,
                          float* __restrict__ out)
{
    const int n     = blockIdx.x;
    const int tid   = threadIdx.x;
    const int wv    = tid >> 6;
    const int lane  = tid & 63;
    const int arow  = lane & 31;          // candidate row (A) / token col (B)
    const int khalf = (lane >> 5) * 8;

    __shared__ __align__(16) short Ah[NC * AST];   // 18.7 KB bf16-hi of E*B2
    __shared__ __align__(16) short Al[NC * AST];   // 18.7 KB bf16-lo
    __shared__ float ts[WIN];
    // Cred (12 KB) is aliased over Ah after the last Ah/Al read (barrier-protected)

    // ---- mask dtype detect, per-wave: int32 has zero bytes at %4!=0 ----
    int found;
    {
        const uint4v* m4 = (const uint4v*)maskp;
        uint4v w = m4[wv * 64 + lane];
        found = (((w.x | w.y | w.z | w.w) & 0xFFFFFF00u) != 0u) ? 1 : 0;
    }
    const bool bytemask = (__ballot(found) != 0ULL);

    // ---- valid-prefix length L, per-wave ----
    int v0m = 0, v1m = 0;
    if (bytemask) {
        const unsigned char* mb = (const unsigned char*)maskp + (size_t)n * WIN;
        v0m = mb[lane] != 0;
        if (lane + 64 < WIN) v1m = mb[lane + 64] != 0;
    } else {
        const int* mi = (const int*)maskp + (size_t)n * WIN;
        v0m = mi[lane] != 0;
        if (lane + 64 < WIN) v1m = mi[lane + 64] != 0;
    }
    const int L  = __popcll(__ballot(v0m)) + __popcll(__ballot(v1m));
    const int Lc = (L > 0) ? L : 1;

    // ---- B1 == B2 check (enables vals-from-scores identity) ----
    int neq = 0;
    #pragma unroll
    for (int k = 0; k < 5; ++k) {
        const int d = lane + 64 * k;
        if (d < D) neq |= (B1[d] != B2[d]) ? 1 : 0;
    }
    const bool beq = (__ballot(neq) == 0ULL);   // block-uniform

    // ---- stage A = E * B_diag2 into LDS as bf16 hi/lo (flat, coalesced) ----
    for (int i = tid; i < NC * 38; i += 256) {
        const int row = i / 38;
        const int c8  = i - row * 38;
        const int col = c8 * 8;
        const float* src = E + ((size_t)n * NC + row) * D + col;
        float v[8];
        float4 q0 = *reinterpret_cast<const float4*>(src);
        float4 b0 = *reinterpret_cast<const float4*>(B2 + col);
        v[0] = q0.x * b0.x; v[1] = q0.y * b0.y;
        v[2] = q0.z * b0.z; v[3] = q0.w * b0.w;
        if (c8 < 37) {
            float4 q1 = *reinterpret_cast<const float4*>(src + 4);
            float4 b1 = *reinterpret_cast<const float4*>(B2 + col + 4);
            v[4] = q1.x * b1.x; v[5] = q1.y * b1.y;
            v[6] = q1.z * b1.z; v[7] = q1.w * b1.w;
        } else {
            v[4] = v[5] = v[6] = v[7] = 0.f;      // cols 300..303 zero
        }
        short8 hi, lo;
        split8(v, hi, lo);
        *reinterpret_cast<short8*>(Ah + row * AST + col) = hi;
        *reinterpret_cast<short8*>(Al + row * AST + col) = lo;
    }

    const int ntiles = (L + 31) >> 5;
    const int t0 = wv * 32;
    const float* Tn = T + (size_t)n * WIN * D;
    const float* bp = Tn + (size_t)min(t0 + arow, Lc - 1) * D;
    const int aoff = min(arow, NC - 1) * AST + khalf;

    // ---- preload approx ring steps 0..3 BEFORE the barrier ----
    float4 q0r[4], q1r[4];
    if (wv < ntiles) {
        #pragma unroll
        for (int s = 0; s < 4; ++s) {
            const int kb = 16 * s + khalf;
            q0r[s] = *reinterpret_cast<const float4*>(bp + kb);
            q1r[s] = *reinterpret_cast<const float4*>(bp + kb + 4);
        }
    }
    __syncthreads();                              // #1: A staged

    // ---- APPROX score GEMM (hi*hi only): selection-grade (v14-verified) ----
    float m = NEGV;
    if (wv < ntiles) {
        f32x16 ca;
        #pragma unroll
        for (int r = 0; r < 16; ++r) ca[r] = 0.f;
        #pragma unroll
        for (int s = 0; s < NKS; ++s) {
            const int slot = s & 3;
            float4 q0 = q0r[slot], q1 = q1r[slot];
            if (s + 4 < NKS) {
                const int kb2 = 16 * (s + 4) + khalf;
                q0r[slot] = *reinterpret_cast<const float4*>(bp + kb2);
                q1r[slot] = (kb2 + 8 <= D)
                          ? *reinterpret_cast<const float4*>(bp + kb2 + 4)
                          : make_float4(0.f, 0.f, 0.f, 0.f);
            }
            short8 ah = *reinterpret_cast<const short8*>(Ah + aoff + 16 * s);
            short8 bh;
            bh[0] = (short)bftrunc(q0.x); bh[1] = (short)bftrunc(q0.y);
            bh[2] = (short)bftrunc(q0.z); bh[3] = (short)bftrunc(q0.w);
            bh[4] = (short)bftrunc(q1.x); bh[5] = (short)bftrunc(q1.y);
            bh[6] = (short)bftrunc(q1.z); bh[7] = (short)bftrunc(q1.w);
            ca = __builtin_amdgcn_mfma_f32_32x32x16_bf16(ah, bh, ca, 0, 0, 0);
        }
        if (lane >= 32) { ca[14] = -__builtin_inff(); ca[15] = -__builtin_inff(); }
        m = ca[0];
        #pragma unroll
        for (int r = 1; r < 16; ++r) m = fmaxf(m, ca[r]);
        m = fmaxf(m, __shfl_xor(m, 32));
    }
    if (lane < 32 && t0 + arow < WIN)
        ts[t0 + arow] = (wv < ntiles && t0 + arow < L) ? m : NEGV;
    __syncthreads();                              // #2: ts complete

    // ---- redundant per-wave top-25 on approx scores (lower-index tie-break) ----
    const float NINF = -__builtin_inff();
    float va = ts[lane];
    float vb = (lane + 64 < WIN) ? ts[lane + 64] : NINF;
    int ixr = 0;
    for (int t = 0; t < TOPK; ++t) {
        float v0; int i0;
        if (vb > va) { v0 = vb; i0 = lane + 64; } else { v0 = va; i0 = lane; }
        #pragma unroll
        for (int s = 32; s >= 1; s >>= 1) {
            float ov = __shfl_xor(v0, s);
            int   oi = __shfl_xor(i0, s);
            if (ov > v0 || (ov == v0 && oi < i0)) { v0 = ov; i0 = oi; }
        }
        if (lane == t) ixr = i0;
        if (i0 == lane) va = NINF;
        else if (i0 == lane + 64) vb = NINF;
    }
    // column view: col = arow; winner token per column (cols 25-31 dup of 24, p=0)
    const int bidx_col = __shfl(ixr, min(arow, TOPK - 1));
    const bool colok = (arow < TOPK) && (bidx_col < L);

    // ---- EXACT rescore of the winner tile, K-SPLIT across all 4 waves ----
    f32x16 c;
    #pragma unroll
    for (int r = 0; r < 16; ++r) c[r] = 0.f;
    {
        const float* wp = Tn + (size_t)bidx_col * D;
        const int ks0 = wv * 5;                   // waves 0-2: 5 steps, wave 3: 4
        float4 e0s[5], e1s[5];
        #pragma unroll
        for (int s5 = 0; s5 < 5; ++s5) {          // batch all loads up-front
            e0s[s5] = make_float4(0.f, 0.f, 0.f, 0.f);
            e1s[s5] = make_float4(0.f, 0.f, 0.f, 0.f);
            const int s = ks0 + s5;
            if (s < NKS) {
                const int kb = 16 * s + khalf;
                e0s[s5] = *reinterpret_cast<const float4*>(wp + kb);
                if (kb + 8 <= D)
                    e1s[s5] = *reinterpret_cast<const float4*>(wp + kb + 4);
            }
        }
        #pragma unroll
        for (int s5 = 0; s5 < 5; ++s5) {
            const int s = ks0 + s5;
            if (s < NKS) {
                short8 ah = *reinterpret_cast<const short8*>(Ah + aoff + 16 * s);
                short8 al = *reinterpret_cast<const short8*>(Al + aoff + 16 * s);
                float v[8] = {e0s[s5].x, e0s[s5].y, e0s[s5].z, e0s[s5].w,
                              e1s[s5].x, e1s[s5].y, e1s[s5].z, e1s[s5].w};
                short8 bh, bl;
                split8(v, bh, bl);
                c = __builtin_amdgcn_mfma_f32_32x32x16_bf16(ah, bh, c, 0, 0, 0);
                c = __builtin_amdgcn_mfma_f32_32x32x16_bf16(al, bh, c, 0, 0, 0);
                c = __builtin_amdgcn_mfma_f32_32x32x16_bf16(ah, bl, c, 0, 0, 0);
            }
        }
    }
    __syncthreads();                              // #3: all Ah/Al reads done -> alias safe

    float* CredF = (float*)Ah;                    // 12 KB partial buffer over dead Ah
    if (wv > 0) {
        #pragma unroll
        for (int q = 0; q < 4; ++q) {
            const int rq = 2 * q + (lane >> 5);
            *reinterpret_cast<float4*>(&CredF[(((wv - 1) * 8 + rq) * 32 + arow) * 4]) =
                make_float4(c[4 * q], c[4 * q + 1], c[4 * q + 2], c[4 * q + 3]);
        }
    }
    __syncthreads();                              // #4: partials visible
    if (wv != 0) return;                          // waves 1-3 retire

    // ---- wave 0: sum K-partials -> exact S tile ----
    #pragma unroll
    for (int w = 0; w < 3; ++w) {
        #pragma unroll
        for (int q = 0; q < 4; ++q) {
            const int rq = 2 * q + (lane >> 5);
            float4 r4 = *reinterpret_cast<const float4*>(
                            &CredF[((w * 8 + rq) * 32 + arow) * 4]);
            c[4 * q]     += r4.x;
            c[4 * q + 1] += r4.y;
            c[4 * q + 2] += r4.z;
            c[4 * q + 3] += r4.w;
        }
    }
    // exact per-winner token score: max over candidate rows (pad rows -> -inf)
    if (lane >= 32) { c[14] = NINF; c[15] = NINF; }
    float mt = c[0];
    #pragma unroll
    for (int r = 1; r < 16; ++r) mt = fmaxf(mt, c[r]);
    mt = fmaxf(mt, __shfl_xor(mt, 32));
    mt = colok ? mt : NEGV;                       // masked/dup winners -> exact -1e10

    // ---- exact softmax over 25 winners (per-half butterflies; halves identical) ----
    float mx = mt;
    #pragma unroll
    for (int s = 16; s >= 1; s >>= 1) mx = fmaxf(mx, __shfl_xor(mx, s));
    float p = (arow < TOPK) ? expf(mt - mx) : 0.f;
    float s1 = p;
    #pragma unroll
    for (int s = 16; s >= 1; s >>= 1) s1 += __shfl_xor(s1, s);
    p = p / s1;
    float s2 = p;   // reference renormalizes a second time
    #pragma unroll
    for (int s = 16; s >= 1; s >>= 1) s2 += __shfl_xor(s2, s);
    p = p / s2;

    if (beq) {
        // ---- vals[row] = sum_t p_t * S[row,t]: butterfly of p*c over columns ----
        float vacc[16];
        #pragma unroll
        for (int r = 0; r < 16; ++r) {
            float s = p * c[r];
            s += __shfl_xor(s, 1);  s += __shfl_xor(s, 2);
            s += __shfl_xor(s, 4);  s += __shfl_xor(s, 8);
            s += __shfl_xor(s, 16);
            vacc[r] = s;
        }
        if ((lane & 31) == 0) {                   // lanes 0 and 32
            #pragma unroll
            for (int r = 0; r < 16; ++r) {
                const int row = (r & 3) + 8 * (r >> 2) + 4 * (lane >> 5);
                if (row < NC) out[(size_t)n * NC + row] = vacc[r];
            }
        }
    } else {
        // ---- fallback (B1 != B2): fcs + vals, single-wave, register-resident ----
        float fc[5] = {0.f, 0.f, 0.f, 0.f, 0.f};
        for (int t = 0; t < TOPK; ++t) {
            const float pb = __shfl(p, t);
            const int   ib = __shfl(bidx_col, t);
            const float* Trow = Tn + (size_t)ib * D;
            #pragma unroll
            for (int c5 = 0; c5 < 5; ++c5) {
                const int dim = c5 * 64 + lane;
                if (dim < D) fc[c5] += pb * Trow[dim];
            }
        }
        float acc2[NC];
        #pragma unroll
        for (int cc = 0; cc < NC; ++cc) acc2[cc] = 0.f;
        #pragma unroll
        for (int c5 = 0; c5 < 5; ++c5) {
            const int dim  = c5 * 64 + lane;
            const int dimc = min(dim, D - 1);
            const float g  = (dim < D) ? B1[dim] * fc[c5] : 0.f;
            const float* Eb = E + (size_t)n * NC * D + dimc;
            #pragma unroll
            for (int cc = 0; cc < NC; ++cc)
                acc2[cc] += Eb[(size_t)cc * D] * g;
        }
        #pragma unroll
        for (int cc = 0; cc < NC; ++cc) {
            float s = acc2[cc];
            #pragma unroll
            for (int sft = 32; sft >= 1; sft >>= 1) s += __shfl_xor(s, sft);
            if (lane == cc) out[(size_t)n * NC + cc] = s;
        }
    }
}

extern "C" void kernel_launch(void* const* d_in, const int* in_sizes, int n_in,
                              void* d_out, int out_size, void* d_ws, size_t ws_size,
                              hipStream_t stream)
{
    const float* E  = (const float*)d_in[0];
    const float* T  = (const float*)d_in[1];
    const void*  M  = d_in[2];
    const float* B1 = (const float*)d_in[3];
    const float* B2 = (const float*)d_in[4];
    float* out = (float*)d_out;
    const int n = in_sizes[0] / (NC * D);   // number of mentions
    fused_mention_kernel<<<n, 256, 0, stream>>>(E, T, M, B1, B2, out);
}